// Round 12
// baseline (138.573 us; speedup 1.0000x reference)
//
#include <hip/hip_runtime.h>
#include <hip/hip_bf16.h>

// Self-guided-filter loss, fused per 32x32 tile. v12 = v11's 6-blocks/CU plan
// with the spill fixed: the two stage-1 halves run in a RUNTIME loop (single
// code instance; v11's duplicated macro bodies caused a 121MB scratch spill).
//  - per half: P2 global -> h1 (31 rows x 44) horiz 11-sums; P4 vert 11-sums
//    -> A,B rows Q0..Q0+20 (reg-saved subtract rows).
//  - P6: horiz 11-sums A,B -> h2 (aliases h1 region); 168 tasks.
//  - P7: direct 11-tap vertical over h2 + finalize; 256 tasks; flit in regs.
//  - XCD-chunked bijective block swizzle.
// LDS 26,880 B -> 6 blocks/CU (24 waves). (8,3,512,512) fp32, r=5, eps=1e-6.

#define W 512
#define TB 32
#define H1STR 44   // h1: 31 rows, cols 0..41 valid
#define ABSTR 44   // A,B: 42 rows, cols 0..41 valid (42,43 junk, never consumed)
#define H2STR 36   // h2: 42 rows, cols 0..31

// Region1: h1 (stage 1) / h2 (stage 2); lifetimes disjoint. size 3024.
#define O_H1X 0        // 31*44 = 1364
#define O_H1Y 1364
#define O_H2A 0        // 42*36 = 1512
#define O_H2B 1512
// Region2: A,B
#define O_A   3024     // 42*44 = 1848
#define O_B   4872
#define S_FLOATS 6720  // 26,880 B -> 6 blocks/CU

#define NBLK_X 16
#define NBLK_Y 16
#define NPLANES 24
#define NWG (NBLK_X*NBLK_Y*NPLANES)     // 6144, % 8 == 0
#define NPARTIALS NWG
#define TOTAL_ELEMS 6291456.0
#define INV121 (1.0f/121.0f)

__device__ __forceinline__ float4 ld4(const float* p) { return *(const float4*)p; }

__global__ __launch_bounds__(256, 4) void sgf_loss_kernel(
    const float* __restrict__ gen, const float* __restrict__ ir,
    const float* __restrict__ vi, float* __restrict__ partials)
{
    __shared__ __align__(16) float S[S_FLOATS];
    const int tid = threadIdx.x;

    // XCD-chunked bijective swizzle (NWG % 8 == 0)
    const int bid = blockIdx.x;
    const int swz = (bid & 7) * (NWG / 8) + (bid >> 3);
    const int tx0 = (swz & (NBLK_X - 1)) * TB;
    const int ty0 = ((swz / NBLK_X) & (NBLK_Y - 1)) * TB;
    const size_t pbase = (size_t)(swz / (NBLK_X * NBLK_Y)) * (W * W);

    float acc = 0.0f;
    float F0 = 0.f, F1 = 0.f, F2 = 0.f, F3 = 0.f;   // flit state (named regs)

    #pragma unroll 1
    for (int img = 0; img < 3; ++img) {
        const float* __restrict__ X =
            (img == 0 ? ir : (img == 1 ? vi : gen)) + pbase;

        __syncthreads();   // prev P7's h2 reads (region1) done before P2 writes

        // ======== STAGE 1: two vertical halves, runtime loop (no spill) ======
        #pragma unroll 1
        for (int half = 0; half < 2; ++half) {
            const int Q0 = 21 * half;                 // A/B row base
            const int IMGROW0 = ty0 - 10 + 21 * half; // h1 row 0 <-> this img row

            // ---- P2: global -> h1 horizontal 11-sums of x, x^2. 186 tasks:
            // 31 rows x 6 col-groups (cg<5: 8 outputs, cg==5: 2 outputs).
            if (tid < 186) {
                int r = tid / 6, cg = tid - r * 6;
                int j0 = cg * 8;
                float* hx = &S[O_H1X + r * H1STR + j0];
                float* hy = &S[O_H1Y + r * H1STR + j0];
                int gy = IMGROW0 + r;
                float w[20];
                if ((unsigned)gy < (unsigned)W) {
                    const float* Xr = X + (size_t)gy * W;
                    int gx0 = tx0 - 12 + j0;           // 16B-aligned
                    if (gx0 >= 0 && gx0 + 20 <= W) {
                        const float4* p = (const float4*)(Xr + gx0);
                        float4 v0 = p[0], v1 = p[1], v2 = p[2], v3 = p[3], v4 = p[4];
                        w[0]=v0.x;  w[1]=v0.y;  w[2]=v0.z;  w[3]=v0.w;
                        w[4]=v1.x;  w[5]=v1.y;  w[6]=v1.z;  w[7]=v1.w;
                        w[8]=v2.x;  w[9]=v2.y;  w[10]=v2.z; w[11]=v2.w;
                        w[12]=v3.x; w[13]=v3.y; w[14]=v3.z; w[15]=v3.w;
                        w[16]=v4.x; w[17]=v4.y; w[18]=v4.z; w[19]=v4.w;
                    } else {
                        #pragma unroll
                        for (int k = 0; k < 20; ++k) {
                            int gx = gx0 + k;
                            w[k] = ((unsigned)gx < (unsigned)W) ? Xr[gx] : 0.f;
                        }
                    }
                } else {
                    #pragma unroll
                    for (int k = 0; k < 20; ++k) w[k] = 0.f;
                }
                float o[8], u[8];
                float s = w[2]+w[3]+w[4]+w[5]+w[6]+w[7]+w[8]+w[9]+w[10]+w[11]+w[12];
                o[0] = s;
                #pragma unroll
                for (int k = 1; k < 8; ++k) { s += w[12+k] - w[1+k]; o[k] = s; }
                float sq[20];
                #pragma unroll
                for (int k = 2; k < 20; ++k) sq[k] = w[k] * w[k];
                float s2 = sq[2]+sq[3]+sq[4]+sq[5]+sq[6]+sq[7]+sq[8]+sq[9]+sq[10]+sq[11]+sq[12];
                u[0] = s2;
                #pragma unroll
                for (int k = 1; k < 8; ++k) { s2 += sq[12+k] - sq[1+k]; u[k] = s2; }
                if (cg < 5) {
                    *(float4*)hx       = make_float4(o[0], o[1], o[2], o[3]);
                    *(float4*)(hx + 4) = make_float4(o[4], o[5], o[6], o[7]);
                    *(float4*)hy       = make_float4(u[0], u[1], u[2], u[3]);
                    *(float4*)(hy + 4) = make_float4(u[4], u[5], u[6], u[7]);
                } else {
                    *(float2*)hx = make_float2(o[0], o[1]);   // cols 40,41
                    *(float2*)hy = make_float2(u[0], u[1]);
                }
            }
            __syncthreads();

            // ---- P4: vertical 11-sums over h1 -> A,B rows Q0..Q0+20. 77 tasks:
            // chunk 0..6 (3 rows), cg 0..10 (cols 4cg..4cg+3); sub-rows in regs.
            if (tid < 77) {
                int chunk = tid / 11, cg = tid - chunk * 11;
                int rb0 = chunk * 3, c4 = cg * 4;
                float mv0 = ((unsigned)(tx0-5+c4+0) < (unsigned)W) ? INV121 : 0.f;
                float mv1 = ((unsigned)(tx0-5+c4+1) < (unsigned)W) ? INV121 : 0.f;
                float mv2 = ((unsigned)(tx0-5+c4+2) < (unsigned)W) ? INV121 : 0.f;
                float mv3 = ((unsigned)(tx0-5+c4+3) < (unsigned)W) ? INV121 : 0.f;
                const float* hx = &S[O_H1X + c4];
                const float* hy = &S[O_H1Y + c4];
                float4 sX0 = ld4(hx + (rb0+0)*H1STR), sY0 = ld4(hy + (rb0+0)*H1STR);
                float4 sX1 = ld4(hx + (rb0+1)*H1STR), sY1 = ld4(hy + (rb0+1)*H1STR);
                float4 sX2 = ld4(hx + (rb0+2)*H1STR), sY2 = ld4(hy + (rb0+2)*H1STR);
                float sx0 = sX0.x + sX1.x + sX2.x, sy0 = sY0.x + sY1.x + sY2.x;
                float sx1 = sX0.y + sX1.y + sX2.y, sy1 = sY0.y + sY1.y + sY2.y;
                float sx2 = sX0.z + sX1.z + sX2.z, sy2 = sY0.z + sY1.z + sY2.z;
                float sx3 = sX0.w + sX1.w + sX2.w, sy3 = sY0.w + sY1.w + sY2.w;
                #pragma unroll
                for (int d = 3; d < 10; ++d) {
                    float4 xn = ld4(hx + (rb0+d)*H1STR);
                    float4 yn = ld4(hy + (rb0+d)*H1STR);
                    sx0+=xn.x; sx1+=xn.y; sx2+=xn.z; sx3+=xn.w;
                    sy0+=yn.x; sy1+=yn.y; sy2+=yn.z; sy3+=yn.w;
                }
#define P4_ROW(J, SUBX, SUBY, DOSUB)                                          \
                {                                                             \
                    int q = Q0 + rb0 + (J);                                   \
                    float4 xn = ld4(hx + (rb0+10+(J))*H1STR);                 \
                    float4 yn = ld4(hy + (rb0+10+(J))*H1STR);                 \
                    sx0+=xn.x; sx1+=xn.y; sx2+=xn.z; sx3+=xn.w;               \
                    sy0+=yn.x; sy1+=yn.y; sy2+=yn.z; sy3+=yn.w;               \
                    int gy = ty0 - 5 + q;                                     \
                    float4 av, bv;                                            \
                    if ((unsigned)gy < (unsigned)W) {                         \
                        float m0=sx0*mv0, c0=sy0*mv0, m1=sx1*mv1, c1=sy1*mv1; \
                        float m2=sx2*mv2, c2=sy2*mv2, m3=sx3*mv3, c3=sy3*mv3; \
                        float va0=fmaf(-m0,m0,c0), va1=fmaf(-m1,m1,c1);       \
                        float va2=fmaf(-m2,m2,c2), va3=fmaf(-m3,m3,c3);       \
                        float a0=va0*__builtin_amdgcn_rcpf(va0+1e-6f);        \
                        float a1=va1*__builtin_amdgcn_rcpf(va1+1e-6f);        \
                        float a2=va2*__builtin_amdgcn_rcpf(va2+1e-6f);        \
                        float a3=va3*__builtin_amdgcn_rcpf(va3+1e-6f);        \
                        av = make_float4(a0,a1,a2,a3);                        \
                        bv = make_float4(fmaf(-a0,m0,m0), fmaf(-a1,m1,m1),    \
                                         fmaf(-a2,m2,m2), fmaf(-a3,m3,m3));   \
                    } else { av = make_float4(0.f,0.f,0.f,0.f); bv = av; }    \
                    *(float4*)&S[O_A + q*ABSTR + c4] = av;                    \
                    *(float4*)&S[O_B + q*ABSTR + c4] = bv;                    \
                    if (DOSUB) {                                              \
                        sx0-=SUBX.x; sx1-=SUBX.y; sx2-=SUBX.z; sx3-=SUBX.w;   \
                        sy0-=SUBY.x; sy1-=SUBY.y; sy2-=SUBY.z; sy3-=SUBY.w;   \
                    }                                                         \
                }
                P4_ROW(0, sX0, sY0, 1)
                P4_ROW(1, sX1, sY1, 1)
                P4_ROW(2, sX2, sY2, 0)
#undef P4_ROW
            }
            __syncthreads();
        }

        // ---- P6: horizontal 11-sums of a,b -> h2a,h2b (region1; h1 dead).
        // 168 tasks (r 0..41, cg 0..3 -> 8 output cols each).
        if (tid < 168) {
            int r = tid >> 2, cg = tid & 3;
            int j0 = cg * 8;
            const float* Ap = &S[O_A + r * ABSTR + j0];
            const float* Bp = &S[O_B + r * ABSTR + j0];
            float wa[20], wb[20];
            #pragma unroll
            for (int k = 0; k < 5; ++k) {
                float4 va = ld4(Ap + 4 * k);
                wa[4*k]=va.x; wa[4*k+1]=va.y; wa[4*k+2]=va.z; wa[4*k+3]=va.w;
                float4 vb = ld4(Bp + 4 * k);
                wb[4*k]=vb.x; wb[4*k+1]=vb.y; wb[4*k+2]=vb.z; wb[4*k+3]=vb.w;
            }
            float oa[8], ob[8];
            float s = wa[0]+wa[1]+wa[2]+wa[3]+wa[4]+wa[5]+wa[6]+wa[7]+wa[8]+wa[9]+wa[10];
            oa[0] = s;
            #pragma unroll
            for (int k = 1; k < 8; ++k) { s += wa[10+k] - wa[k-1]; oa[k] = s; }
            float s2 = wb[0]+wb[1]+wb[2]+wb[3]+wb[4]+wb[5]+wb[6]+wb[7]+wb[8]+wb[9]+wb[10];
            ob[0] = s2;
            #pragma unroll
            for (int k = 1; k < 8; ++k) { s2 += wb[10+k] - wb[k-1]; ob[k] = s2; }
            float* da = &S[O_H2A + r * H2STR + j0];
            float* db = &S[O_H2B + r * H2STR + j0];
            *(float4*)da       = make_float4(oa[0], oa[1], oa[2], oa[3]);
            *(float4*)(da + 4) = make_float4(oa[4], oa[5], oa[6], oa[7]);
            *(float4*)db       = make_float4(ob[0], ob[1], ob[2], ob[3]);
            *(float4*)(db + 4) = make_float4(ob[4], ob[5], ob[6], ob[7]);
        }
        __syncthreads();

        // ---- P7: DIRECT 11-tap vertical over h2 -> f; 256 tasks (all waves).
        // r = tid>>3 (out row 0..31), cg = tid&7 (cols 4cg..4cg+3). Bank-uniform.
        {
            int r = tid >> 3, c4 = (tid & 7) * 4;
            const float* ha = &S[O_H2A + c4];
            const float* hb = &S[O_H2B + c4];
            float sa0=0,sa1=0,sa2=0,sa3=0, sb0=0,sb1=0,sb2=0,sb3=0;
            #pragma unroll
            for (int d = 0; d < 11; ++d) {
                float4 a = ld4(ha + (r+d)*H2STR);
                float4 b = ld4(hb + (r+d)*H2STR);
                sa0+=a.x; sa1+=a.y; sa2+=a.z; sa3+=a.w;
                sb0+=b.x; sb1+=b.y; sb2+=b.z; sb3+=b.w;
            }
            float4 xv = ld4(X + (size_t)(ty0 + r) * W + (tx0 + c4));
            float t0 = fmaf(sa0, xv.x, sb0), g0 = fmaf(-t0, INV121, xv.x);
            float t1 = fmaf(sa1, xv.y, sb1), g1 = fmaf(-t1, INV121, xv.y);
            float t2 = fmaf(sa2, xv.z, sb2), g2 = fmaf(-t2, INV121, xv.z);
            float t3 = fmaf(sa3, xv.w, sb3), g3 = fmaf(-t3, INV121, xv.w);
            if (img == 0) {
                F0 = fabsf(g0); F1 = fabsf(g1); F2 = fabsf(g2); F3 = fabsf(g3);
            } else if (img == 1) {
                F0 = fmaxf(F0, fabsf(g0)); F1 = fmaxf(F1, fabsf(g1));
                F2 = fmaxf(F2, fabsf(g2)); F3 = fmaxf(F3, fabsf(g3));
            } else {
                acc += fabsf(g0 - F0) + fabsf(g1 - F1)
                     + fabsf(g2 - F2) + fabsf(g3 - F3);
            }
        }
    } // img loop

    // block reduction: wave shuffle + cross-wave via LDS
    #pragma unroll
    for (int off = 32; off > 0; off >>= 1) acc += __shfl_down(acc, off);
    __syncthreads();                // all P7 LDS reads done before S reuse
    if ((tid & 63) == 0) S[tid >> 6] = acc;
    __syncthreads();
    if (tid == 0)
        partials[swz] = S[0] + S[1] + S[2] + S[3];
}

__global__ __launch_bounds__(256) void sgf_final_reduce(
    const float* __restrict__ partials, float* __restrict__ out)
{
    __shared__ double sd[256];
    int tid = threadIdx.x;
    double s = 0.0;
    for (int i = tid; i < NPARTIALS; i += 256) s += (double)partials[i];
    sd[tid] = s;
    __syncthreads();
    for (int off = 128; off > 0; off >>= 1) {
        if (tid < off) sd[tid] += sd[tid + off];
        __syncthreads();
    }
    if (tid == 0) out[0] = (float)(sd[0] * (1.0 / TOTAL_ELEMS));
}

extern "C" void kernel_launch(void* const* d_in, const int* in_sizes, int n_in,
                              void* d_out, int out_size, void* d_ws, size_t ws_size,
                              hipStream_t stream) {
    const float* gen = (const float*)d_in[0];
    const float* ir  = (const float*)d_in[1];
    const float* vi  = (const float*)d_in[2];
    float* partials = (float*)d_ws;   // 6144 floats = 24 KB

    sgf_loss_kernel<<<dim3(NWG), dim3(256), 0, stream>>>(gen, ir, vi, partials);
    sgf_final_reduce<<<1, dim3(256), 0, stream>>>(partials, (float*)d_out);
}

// Round 13
// 101.778 us; speedup vs baseline: 1.3615x; 1.3615x over previous
//
#include <hip/hip_runtime.h>
#include <hip/hip_bf16.h>

// Self-guided-filter loss, fused per 32x32 tile. v13 = v9 (101us) with:
//  - P7: 2 output rows/task (128 tasks) -> 24 reads per 2 rows (was 44);
//    bank-uniform (slot = 2*r2+d+cg mod 8); flit in 8 named regs.
//  - P4: subtract-rows held in named regs (v10-proven, no spill).
//  - H1STR 48 -> 52: P2 write quad-slots cover odd+even (was all-even 2-way).
// LDS 36,416 B -> 4 blocks/CU. XCD-chunked bijective swizzle.
// (8,3,512,512) fp32, RADIUS=5 (k=11), EPS=1e-6.

#define W 512
#define TB 32
#define H1STR 52   // h1: 52 rows, cols 0..41 valid (42..51 junk, never consumed)
#define ABSTR 44   // A,B: 42 rows, cols 0..41 valid (42,43 junk, never consumed)
#define H2STR 36   // h2: 42 rows, cols 0..31

#define O_H1X 0        // 52*52 = 2704
#define O_H1Y 2704
#define O_A   5408     // 42*44 = 1848
#define O_B   7256
#define O_H2A 0        // aliases h1x (dead after P4); 42*36 = 1512
#define O_H2B 2704     // aliases h1y
#define S_FLOATS 9104  // 36,416 B -> 4 blocks/CU

#define NBLK_X 16
#define NBLK_Y 16
#define NPLANES 24
#define NWG (NBLK_X*NBLK_Y*NPLANES)     // 6144, % 8 == 0
#define NPARTIALS NWG
#define TOTAL_ELEMS 6291456.0
#define INV121 (1.0f/121.0f)

__device__ __forceinline__ float4 ld4(const float* p) { return *(const float4*)p; }

__global__ __launch_bounds__(256, 4) void sgf_loss_kernel(
    const float* __restrict__ gen, const float* __restrict__ ir,
    const float* __restrict__ vi, float* __restrict__ partials)
{
    __shared__ __align__(16) float S[S_FLOATS];
    const int tid = threadIdx.x;

    // XCD-chunked bijective swizzle (NWG % 8 == 0)
    const int bid = blockIdx.x;
    const int swz = (bid & 7) * (NWG / 8) + (bid >> 3);
    const int tx0 = (swz & (NBLK_X - 1)) * TB;
    const int ty0 = ((swz / NBLK_X) & (NBLK_Y - 1)) * TB;
    const size_t pbase = (size_t)(swz / (NBLK_X * NBLK_Y)) * (W * W);

    float acc = 0.0f;
    // flit state: 8 named regs (threads tid<128; 2 rows x 4 cols each)
    float F00=0,F01=0,F02=0,F03=0, F10=0,F11=0,F12=0,F13=0;

    #pragma unroll 1
    for (int img = 0; img < 3; ++img) {
        const float* __restrict__ X =
            (img == 0 ? ir : (img == 1 ? vi : gen)) + pbase;

        __syncthreads();   // h2 (aliased h1) reads in prev P7 done before P2 writes

        // ---- P2: global -> h1 horizontal 11-sums of x and x^2 (v9 verbatim,
        // stride 52). 312 tasks: 52 rows x 6 col-groups of 8.
        for (int t = tid; t < 312; t += 256) {
            int r = t / 6, cg = t - r * 6;
            int j0 = cg * 8;
            float* hx = &S[O_H1X + r * H1STR + j0];
            float* hy = &S[O_H1Y + r * H1STR + j0];
            int gy = ty0 - 10 + r;
            if ((unsigned)gy >= (unsigned)W) {
                float4 z = make_float4(0.f, 0.f, 0.f, 0.f);
                *(float4*)hx = z; *(float4*)(hx + 4) = z;
                *(float4*)hy = z; *(float4*)(hy + 4) = z;
                continue;
            }
            const float* Xr = X + (size_t)gy * W;
            int gx0 = tx0 - 12 + j0;           // 16B-aligned
            float w[20];
            if (gx0 >= 0 && gx0 + 20 <= W) {
                const float4* p = (const float4*)(Xr + gx0);
                float4 v0 = p[0], v1 = p[1], v2 = p[2], v3 = p[3], v4 = p[4];
                w[0]=v0.x;  w[1]=v0.y;  w[2]=v0.z;  w[3]=v0.w;
                w[4]=v1.x;  w[5]=v1.y;  w[6]=v1.z;  w[7]=v1.w;
                w[8]=v2.x;  w[9]=v2.y;  w[10]=v2.z; w[11]=v2.w;
                w[12]=v3.x; w[13]=v3.y; w[14]=v3.z; w[15]=v3.w;
                w[16]=v4.x; w[17]=v4.y; w[18]=v4.z; w[19]=v4.w;
            } else {
                #pragma unroll
                for (int k = 0; k < 20; ++k) {
                    int gx = gx0 + k;
                    w[k] = ((unsigned)gx < (unsigned)W) ? Xr[gx] : 0.f;
                }
            }
            float o[8], u[8];
            float s = w[2]+w[3]+w[4]+w[5]+w[6]+w[7]+w[8]+w[9]+w[10]+w[11]+w[12];
            o[0] = s;
            #pragma unroll
            for (int k = 1; k < 8; ++k) { s += w[12+k] - w[1+k]; o[k] = s; }
            float sq[20];
            #pragma unroll
            for (int k = 2; k < 20; ++k) sq[k] = w[k] * w[k];
            float s2 = sq[2]+sq[3]+sq[4]+sq[5]+sq[6]+sq[7]+sq[8]+sq[9]+sq[10]+sq[11]+sq[12];
            u[0] = s2;
            #pragma unroll
            for (int k = 1; k < 8; ++k) { s2 += sq[12+k] - sq[1+k]; u[k] = s2; }
            *(float4*)hx       = make_float4(o[0], o[1], o[2], o[3]);
            *(float4*)(hx + 4) = make_float4(o[4], o[5], o[6], o[7]);
            *(float4*)hy       = make_float4(u[0], u[1], u[2], u[3]);
            *(float4*)(hy + 4) = make_float4(u[4], u[5], u[6], u[7]);
        }
        __syncthreads();

        // ---- P4: vertical 11-sums over h1 -> A,B. 154 tasks, 3-row chains;
        // subtract-rows (d=0..2) in named regs (v10-proven).
        if (tid < 154) {
            int chunk = tid / 11, cg = tid - chunk * 11;
            int q0 = chunk * 3, c4 = cg * 4;
            float mv0 = ((unsigned)(tx0-5+c4+0) < (unsigned)W) ? INV121 : 0.f;
            float mv1 = ((unsigned)(tx0-5+c4+1) < (unsigned)W) ? INV121 : 0.f;
            float mv2 = ((unsigned)(tx0-5+c4+2) < (unsigned)W) ? INV121 : 0.f;
            float mv3 = ((unsigned)(tx0-5+c4+3) < (unsigned)W) ? INV121 : 0.f;
            const float* hx = &S[O_H1X + c4];
            const float* hy = &S[O_H1Y + c4];
            float4 sX0 = ld4(hx + (q0+0)*H1STR), sY0 = ld4(hy + (q0+0)*H1STR);
            float4 sX1 = ld4(hx + (q0+1)*H1STR), sY1 = ld4(hy + (q0+1)*H1STR);
            float4 sX2 = ld4(hx + (q0+2)*H1STR), sY2 = ld4(hy + (q0+2)*H1STR);
            float sx0 = sX0.x + sX1.x + sX2.x, sy0 = sY0.x + sY1.x + sY2.x;
            float sx1 = sX0.y + sX1.y + sX2.y, sy1 = sY0.y + sY1.y + sY2.y;
            float sx2 = sX0.z + sX1.z + sX2.z, sy2 = sY0.z + sY1.z + sY2.z;
            float sx3 = sX0.w + sX1.w + sX2.w, sy3 = sY0.w + sY1.w + sY2.w;
            #pragma unroll
            for (int d = 3; d < 10; ++d) {
                float4 xn = ld4(hx + (q0+d)*H1STR);
                float4 yn = ld4(hy + (q0+d)*H1STR);
                sx0+=xn.x; sx1+=xn.y; sx2+=xn.z; sx3+=xn.w;
                sy0+=yn.x; sy1+=yn.y; sy2+=yn.z; sy3+=yn.w;
            }
#define P4_ROW(J, SUBX, SUBY, DOSUB)                                          \
            {                                                                 \
                int q = q0 + (J);                                             \
                float4 xn = ld4(hx + (q+10)*H1STR);                           \
                float4 yn = ld4(hy + (q+10)*H1STR);                           \
                sx0+=xn.x; sx1+=xn.y; sx2+=xn.z; sx3+=xn.w;                   \
                sy0+=yn.x; sy1+=yn.y; sy2+=yn.z; sy3+=yn.w;                   \
                int gy = ty0 - 5 + q;                                         \
                float4 av, bv;                                                \
                if ((unsigned)gy < (unsigned)W) {                             \
                    float m0=sx0*mv0, c0=sy0*mv0, m1=sx1*mv1, c1=sy1*mv1;     \
                    float m2=sx2*mv2, c2=sy2*mv2, m3=sx3*mv3, c3=sy3*mv3;     \
                    float va0=fmaf(-m0,m0,c0), va1=fmaf(-m1,m1,c1);           \
                    float va2=fmaf(-m2,m2,c2), va3=fmaf(-m3,m3,c3);           \
                    float a0=va0*__builtin_amdgcn_rcpf(va0+1e-6f);            \
                    float a1=va1*__builtin_amdgcn_rcpf(va1+1e-6f);            \
                    float a2=va2*__builtin_amdgcn_rcpf(va2+1e-6f);            \
                    float a3=va3*__builtin_amdgcn_rcpf(va3+1e-6f);            \
                    av = make_float4(a0,a1,a2,a3);                            \
                    bv = make_float4(fmaf(-a0,m0,m0), fmaf(-a1,m1,m1),        \
                                     fmaf(-a2,m2,m2), fmaf(-a3,m3,m3));       \
                } else { av = make_float4(0.f,0.f,0.f,0.f); bv = av; }        \
                *(float4*)&S[O_A + q*ABSTR + c4] = av;                        \
                *(float4*)&S[O_B + q*ABSTR + c4] = bv;                        \
                if (DOSUB) {                                                  \
                    sx0-=SUBX.x; sx1-=SUBX.y; sx2-=SUBX.z; sx3-=SUBX.w;       \
                    sy0-=SUBY.x; sy1-=SUBY.y; sy2-=SUBY.z; sy3-=SUBY.w;       \
                }                                                             \
            }
            P4_ROW(0, sX0, sY0, 1)
            P4_ROW(1, sX1, sY1, 1)
            P4_ROW(2, sX2, sY2, 0)
#undef P4_ROW
        }
        __syncthreads();

        // ---- P6: horizontal 11-sums of a,b -> h2a,h2b (v9 verbatim).
        // 168 tasks (r 0..41, cg 0..3 -> 8 output cols each).
        if (tid < 168) {
            int r = tid >> 2, cg = tid & 3;
            int j0 = cg * 8;
            const float* Ap = &S[O_A + r * ABSTR + j0];
            const float* Bp = &S[O_B + r * ABSTR + j0];
            float wa[20], wb[20];
            #pragma unroll
            for (int k = 0; k < 5; ++k) {
                float4 va = ld4(Ap + 4 * k);
                wa[4*k]=va.x; wa[4*k+1]=va.y; wa[4*k+2]=va.z; wa[4*k+3]=va.w;
                float4 vb = ld4(Bp + 4 * k);
                wb[4*k]=vb.x; wb[4*k+1]=vb.y; wb[4*k+2]=vb.z; wb[4*k+3]=vb.w;
            }
            float oa[8], ob[8];
            float s = wa[0]+wa[1]+wa[2]+wa[3]+wa[4]+wa[5]+wa[6]+wa[7]+wa[8]+wa[9]+wa[10];
            oa[0] = s;
            #pragma unroll
            for (int k = 1; k < 8; ++k) { s += wa[10+k] - wa[k-1]; oa[k] = s; }
            float s2 = wb[0]+wb[1]+wb[2]+wb[3]+wb[4]+wb[5]+wb[6]+wb[7]+wb[8]+wb[9]+wb[10];
            ob[0] = s2;
            #pragma unroll
            for (int k = 1; k < 8; ++k) { s2 += wb[10+k] - wb[k-1]; ob[k] = s2; }
            float* da = &S[O_H2A + r * H2STR + j0];
            float* db = &S[O_H2B + r * H2STR + j0];
            *(float4*)da       = make_float4(oa[0], oa[1], oa[2], oa[3]);
            *(float4*)(da + 4) = make_float4(oa[4], oa[5], oa[6], oa[7]);
            *(float4*)db       = make_float4(ob[0], ob[1], ob[2], ob[3]);
            *(float4*)(db + 4) = make_float4(ob[4], ob[5], ob[6], ob[7]);
        }
        __syncthreads();

        // ---- P7: vertical 11-taps over h2, 2 OUTPUT ROWS per task. 128 tasks
        // (2 waves): r2 = tid>>3 -> rows 2*r2, 2*r2+1; cg = tid&7 -> cols 4cg.
        // Reads rows r..r+11 once (24 b128); row r+1 sums = row r sums - first + last.
        if (tid < 128) {
            int r = (tid >> 3) * 2, c4 = (tid & 7) * 4;
            const float* ha = &S[O_H2A + c4];
            const float* hb = &S[O_H2B + c4];
            float4 aF = ld4(ha + r * H2STR);         // row r (d=0)
            float4 bF = ld4(hb + r * H2STR);
            float sa0=aF.x, sa1=aF.y, sa2=aF.z, sa3=aF.w;
            float sb0=bF.x, sb1=bF.y, sb2=bF.z, sb3=bF.w;
            #pragma unroll
            for (int d = 1; d < 11; ++d) {
                float4 a = ld4(ha + (r+d)*H2STR);
                float4 b = ld4(hb + (r+d)*H2STR);
                sa0+=a.x; sa1+=a.y; sa2+=a.z; sa3+=a.w;
                sb0+=b.x; sb1+=b.y; sb2+=b.z; sb3+=b.w;
            }
            float4 aL = ld4(ha + (r+11)*H2STR);      // row r+11 (for row r+1)
            float4 bL = ld4(hb + (r+11)*H2STR);
            // row r
            float4 xv0 = ld4(X + (size_t)(ty0 + r) * W + (tx0 + c4));
            float t0 = fmaf(sa0, xv0.x, sb0), g0 = fmaf(-t0, INV121, xv0.x);
            float t1 = fmaf(sa1, xv0.y, sb1), g1 = fmaf(-t1, INV121, xv0.y);
            float t2 = fmaf(sa2, xv0.z, sb2), g2 = fmaf(-t2, INV121, xv0.z);
            float t3 = fmaf(sa3, xv0.w, sb3), g3 = fmaf(-t3, INV121, xv0.w);
            // row r+1 sums
            float ua0 = sa0 - aF.x + aL.x, ub0 = sb0 - bF.x + bL.x;
            float ua1 = sa1 - aF.y + aL.y, ub1 = sb1 - bF.y + bL.y;
            float ua2 = sa2 - aF.z + aL.z, ub2 = sb2 - bF.z + bL.z;
            float ua3 = sa3 - aF.w + aL.w, ub3 = sb3 - bF.w + bL.w;
            float4 xv1 = ld4(X + (size_t)(ty0 + r + 1) * W + (tx0 + c4));
            float u0 = fmaf(ua0, xv1.x, ub0), h0 = fmaf(-u0, INV121, xv1.x);
            float u1 = fmaf(ua1, xv1.y, ub1), h1 = fmaf(-u1, INV121, xv1.y);
            float u2 = fmaf(ua2, xv1.z, ub2), h2 = fmaf(-u2, INV121, xv1.z);
            float u3 = fmaf(ua3, xv1.w, ub3), h3 = fmaf(-u3, INV121, xv1.w);
            if (img == 0) {
                F00 = fabsf(g0); F01 = fabsf(g1); F02 = fabsf(g2); F03 = fabsf(g3);
                F10 = fabsf(h0); F11 = fabsf(h1); F12 = fabsf(h2); F13 = fabsf(h3);
            } else if (img == 1) {
                F00 = fmaxf(F00, fabsf(g0)); F01 = fmaxf(F01, fabsf(g1));
                F02 = fmaxf(F02, fabsf(g2)); F03 = fmaxf(F03, fabsf(g3));
                F10 = fmaxf(F10, fabsf(h0)); F11 = fmaxf(F11, fabsf(h1));
                F12 = fmaxf(F12, fabsf(h2)); F13 = fmaxf(F13, fabsf(h3));
            } else {
                acc += fabsf(g0 - F00) + fabsf(g1 - F01)
                     + fabsf(g2 - F02) + fabsf(g3 - F03)
                     + fabsf(h0 - F10) + fabsf(h1 - F11)
                     + fabsf(h2 - F12) + fabsf(h3 - F13);
            }
        }
    } // img loop

    // block reduction: wave shuffle + cross-wave via LDS (acc nonzero tid<128)
    #pragma unroll
    for (int off = 32; off > 0; off >>= 1) acc += __shfl_down(acc, off);
    __syncthreads();                // all P7 LDS reads done before S reuse
    if ((tid & 63) == 0) S[tid >> 6] = acc;
    __syncthreads();
    if (tid == 0)
        partials[swz] = S[0] + S[1] + S[2] + S[3];
}

__global__ __launch_bounds__(256) void sgf_final_reduce(
    const float* __restrict__ partials, float* __restrict__ out)
{
    __shared__ double sd[256];
    int tid = threadIdx.x;
    double s = 0.0;
    for (int i = tid; i < NPARTIALS; i += 256) s += (double)partials[i];
    sd[tid] = s;
    __syncthreads();
    for (int off = 128; off > 0; off >>= 1) {
        if (tid < off) sd[tid] += sd[tid + off];
        __syncthreads();
    }
    if (tid == 0) out[0] = (float)(sd[0] * (1.0 / TOTAL_ELEMS));
}

extern "C" void kernel_launch(void* const* d_in, const int* in_sizes, int n_in,
                              void* d_out, int out_size, void* d_ws, size_t ws_size,
                              hipStream_t stream) {
    const float* gen = (const float*)d_in[0];
    const float* ir  = (const float*)d_in[1];
    const float* vi  = (const float*)d_in[2];
    float* partials = (float*)d_ws;   // 6144 floats = 24 KB

    sgf_loss_kernel<<<dim3(NWG), dim3(256), 0, stream>>>(gen, ir, vi, partials);
    sgf_final_reduce<<<1, dim3(256), 0, stream>>>(partials, (float*)d_out);
}